// Round 8
// baseline (1017.020 us; speedup 1.0000x reference)
//
#include <hip/hip_runtime.h>

#define HIDDEN 450
#define MAX_NB 15
#define N_ATOMS 20000
#define N_BONDS 40000
#define N_MESS  16000
#define N_MOLS  1000
#define KPAD    512     // concat-K: [feat 0..39 | nei 40..489 | pad]
#define MSTRIDE 456     // message/base row stride = 912B = 57 x 16B chunks

typedef unsigned int uint;
typedef unsigned short ushort;
typedef __bf16 bf16x8 __attribute__((ext_vector_type(8)));
typedef float  f32x4  __attribute__((ext_vector_type(4)));

__device__ __forceinline__ ushort f2bf(float f) {
    uint u = __builtin_bit_cast(uint, f);
    u += 0x7fffu + ((u >> 16) & 1u);     // RNE
    return (ushort)(u >> 16);
}
__device__ __forceinline__ float bfhi(uint w) {
    return __builtin_bit_cast(float, w & 0xffff0000u);
}
__device__ __forceinline__ float bflo(uint w) {
    return __builtin_bit_cast(float, w << 16);
}

// ---------------- pack kernels (run once per launch) ----------------

__global__ __launch_bounds__(256) void pack_tree(const float* __restrict__ tree,
                                                 ushort* __restrict__ tbuf) {
    const int r = blockIdx.x, t = threadIdx.x;
    if (t < 228) {
        uint p = 0;
        if (t < 225) {
            const float2 v = *(const float2*)&tree[(size_t)r * HIDDEN + 2 * t];
            p = (uint)f2bf(v.x) | ((uint)f2bf(v.y) << 16);
        }
        ((uint*)(tbuf + (size_t)r * MSTRIDE))[t] = p;
    }
}

// dst[r][0..63] = bf16(src[r][0..fd-1]) | zeros
__global__ __launch_bounds__(256) void pack_feats(const float* __restrict__ src, int fd,
                                                  ushort* __restrict__ dst, int nrows) {
    const int r = blockIdx.x * 4 + (threadIdx.x >> 6);
    const int t = threadIdx.x & 63;
    if (r >= nrows) return;
    dst[(size_t)r * 64 + t] = (t < fd) ? f2bf(src[(size_t)r * fd + t]) : (ushort)0;
}

__global__ __launch_bounds__(256) void pack_w(const float* __restrict__ W_i,
                                              const float* __restrict__ W_h,
                                              const float* __restrict__ W_o,
                                              ushort* __restrict__ Wcat,
                                              ushort* __restrict__ Wocat) {
    const int n = blockIdx.x;  // 0..511
    for (int c = threadIdx.x; c < KPAD; c += 256) {
        float v = 0.0f, vo = 0.0f;
        if (n < HIDDEN) {
            if (c < 40)       v = W_i[(size_t)n * 40 + c];
            else if (c < 490) v = W_h[(size_t)n * HIDDEN + (c - 40)];
            if (c < 35)       vo = W_o[(size_t)n * 485 + c];
            else if (c >= 40 && c < 490) vo = W_o[(size_t)n * 485 + 35 + (c - 40)];
        }
        Wcat [(size_t)n * KPAD + c] = f2bf(v);
        Wocat[(size_t)n * KPAD + c] = f2bf(vo);
    }
}

// ---------------- static-base precompute: base[r] = sum_{idx<N_MESS} tbuf[idx] ----
__global__ __launch_bounds__(256) void precompute_base(const int* __restrict__ g,
                                                       const ushort* __restrict__ tbuf,
                                                       ushort* __restrict__ base,
                                                       int nrows) {
    const int r = blockIdx.x * 4 + (threadIdx.x >> 6);
    const int lane = threadIdx.x & 63;
    if (r >= nrows) return;
    const int* gr = g + (size_t)r * MAX_NB;
    int idx[MAX_NB];
#pragma unroll
    for (int j = 0; j < MAX_NB; ++j) idx[j] = gr[j];
    if (lane >= 57) return;
    const int off = lane * 8;
    float acc[8] = {};
#pragma unroll
    for (int j = 0; j < MAX_NB; ++j) {
        if (idx[j] < N_MESS) {       // wave-uniform branch
            const uint4 w = *(const uint4*)(tbuf + (size_t)idx[j] * MSTRIDE + off);
            acc[0] += bflo(w.x); acc[1] += bfhi(w.x);
            acc[2] += bflo(w.y); acc[3] += bfhi(w.y);
            acc[4] += bflo(w.z); acc[5] += bfhi(w.z);
            acc[6] += bflo(w.w); acc[7] += bfhi(w.w);
        }
    }
    uint4 p;
    p.x = (uint)f2bf(acc[0]) | ((uint)f2bf(acc[1]) << 16);
    p.y = (uint)f2bf(acc[2]) | ((uint)f2bf(acc[3]) << 16);
    p.z = (uint)f2bf(acc[4]) | ((uint)f2bf(acc[5]) << 16);
    p.w = (uint)f2bf(acc[6]) | ((uint)f2bf(acc[7]) << 16);
    *(uint4*)(base + (size_t)r * MSTRIDE + off) = p;
}

// ---------------- fused gather + MFMA GEMM ----------------
// Per block: 64 rows. Phase 1: gather nei sums (base + dyn gmsg rows) straight
// into the swizzled LDS A-tile (cols 40..495), static feats -> cols 0..39,
// zeros -> 496..511. ONE barrier. Phase 2: 8 waves x (64m x 64n), K = KT*32,
// W direct from L2 with 2-step register prefetch, A-frags from LDS (1-step).
// Phase 3: MODE 0 -> relu -> bf16 gmsg_out rows (+zero pad cols);
//          MODE 1 -> bias+relu -> f32 atomicAdd with equal-mol run merging.
// GATHER=0 (KT=2): A-tile = feats only (init GEMM, K=64).
template <int MODE, int GATHER, int KT>
__global__ __launch_bounds__(512, 2) void fused_mp(
    const int* __restrict__ g, const ushort* __restrict__ base,
    const ushort* __restrict__ feats, const ushort* __restrict__ gin,
    const ushort* __restrict__ W, const float* __restrict__ bias,
    const int* __restrict__ mol_ids, ushort* __restrict__ gout,
    float* __restrict__ aout, int M, int mtiles) {
    __shared__ ushort At[64 * KT * 32];
    const int m_blk = blockIdx.x;
    if (m_blk >= mtiles) return;
    const int m0 = m_blk * 64;
    const int tid  = threadIdx.x;
    const int lane = tid & 63;
    const int wave = tid >> 6;

    // ---- phase 1: build A-tile ----
    if (GATHER) {
#pragma unroll 1
        for (int rr = 0; rr < 8; ++rr) {
            const int row = rr * 8 + wave;
            const int r = min(m0 + row, M - 1);
            const int* gr = g + (size_t)r * MAX_NB;
            int idx[MAX_NB];
#pragma unroll
            for (int j = 0; j < MAX_NB; ++j) idx[j] = gr[j];
            ushort* lrow = At + row * (KT * 32);
            const int sw = row & 7;
            if (lane < 57) {
                const int off = lane * 8;
                const uint4 b4 = *(const uint4*)(base + (size_t)r * MSTRIDE + off);
                float acc[8];
                acc[0] = bflo(b4.x); acc[1] = bfhi(b4.x);
                acc[2] = bflo(b4.y); acc[3] = bfhi(b4.y);
                acc[4] = bflo(b4.z); acc[5] = bfhi(b4.z);
                acc[6] = bflo(b4.w); acc[7] = bfhi(b4.w);
#pragma unroll
                for (int j = 0; j < MAX_NB; ++j) {
                    if (idx[j] >= N_MESS) {   // wave-uniform branch
                        const uint4 w4 = *(const uint4*)(gin +
                            (size_t)(idx[j] - N_MESS) * MSTRIDE + off);
                        acc[0] += bflo(w4.x); acc[1] += bfhi(w4.x);
                        acc[2] += bflo(w4.y); acc[3] += bfhi(w4.y);
                        acc[4] += bflo(w4.z); acc[5] += bfhi(w4.z);
                        acc[6] += bflo(w4.w); acc[7] += bfhi(w4.w);
                    }
                }
                uint4 p;
                p.x = (uint)f2bf(acc[0]) | ((uint)f2bf(acc[1]) << 16);
                p.y = (uint)f2bf(acc[2]) | ((uint)f2bf(acc[3]) << 16);
                p.z = (uint)f2bf(acc[4]) | ((uint)f2bf(acc[5]) << 16);
                p.w = (uint)f2bf(acc[6]) | ((uint)f2bf(acc[7]) << 16);
                *(uint4*)&lrow[((5 + lane) ^ sw) * 8] = p;          // chunks 5..61
            } else if (lane < 62) {
                const int c = lane - 57;                            // chunks 0..4
                const uint4 f = *(const uint4*)(feats + (size_t)r * 64 + c * 8);
                *(uint4*)&lrow[(c ^ sw) * 8] = f;
            } else {
                const uint4 z = {0, 0, 0, 0};                       // chunks 62,63
                *(uint4*)&lrow[(lane ^ sw) * 8] = z;
            }
        }
    } else {
        // KT=2: 8 chunks/row, pure feats (40 real + 24 zero)
        const int row = tid >> 3, c = tid & 7;
        const int r = min(m0 + row, M - 1);
        const uint4 f = *(const uint4*)(feats + (size_t)r * 64 + c * 8);
        *(uint4*)&At[row * (KT * 32) + ((c ^ (row & 7)) * 8)] = f;
    }
    __syncthreads();                        // the ONLY barrier

    // ---- phase 2: GEMM ----
    const int wn = wave * 64;               // wave covers n = wn..wn+63
    const int lr = lane & 15;
    const int lk = lane >> 4;
    const int CPR = KT * 4;

    size_t woff[4];
#pragma unroll
    for (int s = 0; s < 4; ++s)
        woff[s] = (size_t)(wn + s * 16 + lr) * KPAD + lk * 8;

    f32x4 acc[4][4];
#pragma unroll
    for (int i = 0; i < 4; ++i)
#pragma unroll
        for (int j = 0; j < 4; ++j) acc[i][j] = (f32x4){0.f, 0.f, 0.f, 0.f};

    bf16x8 wa[4], wb[4], afa[4];
#pragma unroll
    for (int s = 0; s < 4; ++s) wa[s] = *(const bf16x8*)&W[woff[s]];
#pragma unroll
    for (int s = 0; s < 4; ++s)
        wb[s] = (KT > 1) ? *(const bf16x8*)&W[woff[s] + 32] : wa[s];
#pragma unroll
    for (int mt = 0; mt < 4; ++mt) {
        const int row = mt * 16 + lr;
        afa[mt] = *(const bf16x8*)&At[row * (KT * 32) + ((lk ^ (row & 7)) * 8)];
    }

#pragma unroll
    for (int i = 0; i < KT; ++i) {
        bf16x8 wc[4], afb[4];
        if (i + 2 < KT) {
#pragma unroll
            for (int s = 0; s < 4; ++s)
                wc[s] = *(const bf16x8*)&W[woff[s] + (size_t)(i + 2) * 32];
        }
        if (i + 1 < KT) {
#pragma unroll
            for (int mt = 0; mt < 4; ++mt) {
                const int row = mt * 16 + lr;
                const int chunk = ((i + 1) * 4 + lk) ^ (row & 7);
                afb[mt] = *(const bf16x8*)&At[row * (KT * 32) + chunk * 8];
            }
        }
#pragma unroll
        for (int mt = 0; mt < 4; ++mt)
#pragma unroll
            for (int nt = 0; nt < 4; ++nt)
                acc[mt][nt] = __builtin_amdgcn_mfma_f32_16x16x32_bf16(
                    afa[mt], wa[nt], acc[mt][nt], 0, 0, 0);
        if (i + 1 < KT) {
#pragma unroll
            for (int s = 0; s < 4; ++s) wa[s] = wb[s];
#pragma unroll
            for (int mt = 0; mt < 4; ++mt) afa[mt] = afb[mt];
        }
        if (i + 2 < KT) {
#pragma unroll
            for (int s = 0; s < 4; ++s) wb[s] = wc[s];
        }
    }

    // ---- phase 3: epilogue ----
    const int col_l = lane & 15;
    const int rbase = (lane >> 4) * 4;
#pragma unroll
    for (int mt = 0; mt < 4; ++mt) {
        const int mbase = m0 + mt * 16 + rbase;
        int mol[4];
        if (MODE == 1) {
#pragma unroll
            for (int reg = 0; reg < 4; ++reg)
                mol[reg] = mol_ids[min(mbase + reg, M - 1)];
        }
#pragma unroll
        for (int nt = 0; nt < 4; ++nt) {
            const int n = wn + nt * 16 + col_l;
            if (MODE == 0) {
#pragma unroll
                for (int reg = 0; reg < 4; ++reg) {
                    const int m = mbase + reg;
                    if (m >= M) continue;
                    if (n < HIDDEN)
                        gout[(size_t)m * MSTRIDE + n] = f2bf(fmaxf(acc[mt][nt][reg], 0.0f));
                    else if (n < MSTRIDE)
                        gout[(size_t)m * MSTRIDE + n] = 0;   // keep pad cols zero
                }
            } else {
                if (n >= HIDDEN) continue;
                const float bsum = bias[n];
                float run = 0.0f;
                int cur = mol[0];
#pragma unroll
                for (int reg = 0; reg < 4; ++reg) {
                    const float v = (mbase + reg < M)
                        ? fmaxf(acc[mt][nt][reg] + bsum, 0.0f) : 0.0f;
                    if (mol[reg] != cur) {
                        atomicAdd(&aout[(size_t)cur * HIDDEN + n], run);
                        cur = mol[reg];
                        run = 0.0f;
                    }
                    run += v;
                }
                atomicAdd(&aout[(size_t)cur * HIDDEN + n], run);
            }
        }
    }
}

// ---------------- molecule mean ----------------
__global__ __launch_bounds__(256) void count_atoms(const int* __restrict__ mol_ids,
                                                   float* __restrict__ counts) {
    const int a = blockIdx.x * 256 + threadIdx.x;
    if (a < N_ATOMS) atomicAdd(&counts[mol_ids[a]], 1.0f);
}
__global__ __launch_bounds__(256) void div_counts(float* __restrict__ out,
                                                  const float* __restrict__ counts) {
    const int i = blockIdx.x * 256 + threadIdx.x;
    if (i < N_MOLS * HIDDEN) out[i] = out[i] / counts[i / HIDDEN];
}

extern "C" void kernel_launch(void* const* d_in, const int* in_sizes, int n_in,
                              void* d_out, int out_size, void* d_ws, size_t ws_size,
                              hipStream_t stream) {
    const float* fatoms  = (const float*)d_in[0];
    const float* fbonds  = (const float*)d_in[1];
    const int*   agraph  = (const int*)d_in[2];
    const int*   bgraph  = (const int*)d_in[3];
    const int*   mol_ids = (const int*)d_in[4];
    const float* tree    = (const float*)d_in[6];
    const float* W_i     = (const float*)d_in[7];
    const float* W_h     = (const float*)d_in[8];
    const float* W_o     = (const float*)d_in[9];
    const float* b_o     = (const float*)d_in[10];
    float* out = (float*)d_out;

    ushort* featsB = (ushort*)d_ws;                        // 40000 x 64
    ushort* featsA = featsB + (size_t)N_BONDS * 64;        // 20000 x 64
    ushort* gmsgA  = featsA + (size_t)N_ATOMS * 64;        // 40000 x 456
    ushort* gmsgB  = gmsgA  + (size_t)N_BONDS * MSTRIDE;   // 40000 x 456
    ushort* tbuf   = gmsgB  + (size_t)N_BONDS * MSTRIDE;   // 16000 x 456
    ushort* Wcat   = tbuf   + (size_t)N_MESS  * MSTRIDE;   // 512 x 512
    ushort* Wocat  = Wcat   + (size_t)KPAD * KPAD;         // 512 x 512
    ushort* base_b = Wocat  + (size_t)KPAD * KPAD;         // 40000 x 456
    ushort* base_a = base_b + (size_t)N_BONDS * MSTRIDE;   // 20000 x 456
    float*  counts = (float*)(base_a + (size_t)N_ATOMS * MSTRIDE);

    (void)hipMemsetAsync(d_out, 0, (size_t)N_MOLS * HIDDEN * sizeof(float), stream);
    (void)hipMemsetAsync(counts, 0, N_MOLS * sizeof(float), stream);

    const dim3 blk(256);
    pack_tree <<<N_MESS, blk, 0, stream>>>(tree, tbuf);
    pack_feats<<<(N_BONDS + 3) / 4, blk, 0, stream>>>(fbonds, 40, featsB, N_BONDS);
    pack_feats<<<(N_ATOMS + 3) / 4, blk, 0, stream>>>(fatoms, 35, featsA, N_ATOMS);
    pack_w    <<<KPAD, blk, 0, stream>>>(W_i, W_h, W_o, Wcat, Wocat);
    precompute_base<<<(N_BONDS + 3) / 4, blk, 0, stream>>>(bgraph, tbuf, base_b, N_BONDS);
    precompute_base<<<(N_ATOMS + 3) / 4, blk, 0, stream>>>(agraph, tbuf, base_a, N_ATOMS);

    const int mtB = (N_BONDS + 63) / 64;                   // 625
    const int mtA = (N_ATOMS + 63) / 64;                   // 313
    const dim3 blk512(512);

    // init: gmsgA = relu(feats @ Wcat[:, :64]^T)  (nei cols zero, K=64)
    fused_mp<0, 0, 2><<<mtB, blk512, 0, stream>>>(
        nullptr, nullptr, featsB, nullptr, Wcat,
        nullptr, nullptr, gmsgA, nullptr, N_BONDS, mtB);
    // 5 MP steps, ping-pong A->B->A->B->A->B (statically unrolled, graph-safe)
    ushort* pp[6] = {gmsgA, gmsgB, gmsgA, gmsgB, gmsgA, gmsgB};
    for (int it = 0; it < 5; ++it) {
        fused_mp<0, 1, 16><<<mtB, blk512, 0, stream>>>(
            bgraph, base_b, featsB, pp[it], Wcat,
            nullptr, nullptr, pp[it + 1], nullptr, N_BONDS, mtB);
    }
    // final atom stage: gather(agraph) + W_o GEMM + bias + relu + mol atomics
    fused_mp<1, 1, 16><<<mtA, blk512, 0, stream>>>(
        agraph, base_a, featsA, pp[5], Wocat,
        b_o, mol_ids, nullptr, out, N_ATOMS, mtA);

    count_atoms<<<(N_ATOMS + 255) / 256, blk, 0, stream>>>(mol_ids, counts);
    div_counts <<<(N_MOLS * HIDDEN + 255) / 256, blk, 0, stream>>>(out, counts);
}